// Round 1
// baseline (1597.030 us; speedup 1.0000x reference)
//
#include <hip/hip_runtime.h>
#include <cmath>

#define NTOT 524288
#define KC   256
#define DD   128

typedef __attribute__((ext_vector_type(8))) short bf16x8;
typedef __attribute__((ext_vector_type(4))) float f32x4;

static __device__ __forceinline__ unsigned short f2bf(float f) {
  unsigned int u = __float_as_uint(f);
  u = (u + 0x7fffu + ((u >> 16) & 1u)) >> 16;
  return (unsigned short)u;
}
static __device__ __forceinline__ float bf2f(unsigned short h) {
  return __uint_as_float(((unsigned int)h) << 16);
}

// ---------------- prep: normalize codebook -> bf16 hi/lo split, packed [dgrp][code][8] ----------------
__global__ __launch_bounds__(64) void vq_prep(const float* __restrict__ emb,
                                              unsigned short* __restrict__ ephi,
                                              unsigned short* __restrict__ eplo,
                                              float* __restrict__ pacc_g) {
  const int c = blockIdx.x;
  const int l = threadIdx.x;
  const float a = emb[c * DD + l];
  const float b = emb[c * DD + 64 + l];
  float s = a * a + b * b;
#pragma unroll
  for (int m = 32; m >= 1; m >>= 1) s += __shfl_xor(s, m, 64);
  const float inv = 1.0f / fmaxf(sqrtf(s), 1e-12f);
  if (l < 16) {
#pragma unroll
    for (int j = 0; j < 8; ++j) {
      const float v = emb[c * DD + l * 8 + j] * inv;
      const unsigned short h = f2bf(v);
      const unsigned short lo = f2bf(v - bf2f(h));
      const size_t off = ((size_t)l * KC + c) * 8 + j;
      ephi[off] = h;
      eplo[off] = lo;
    }
  }
  if (l == 0) pacc_g[c] = 0.0f;
}

// ---------------- main: MFMA bf16-split dots + argmax (+fp64 top-3 tie refine) + softmax + gather ----
// One independent wave per 16-row tile; codes are 16 n-fragments of 16x16x32 MFMA.
// C layout (m89-verified): col = lane&15, row = (lane>>4)*4 + reg.
// No __syncthreads in the main loop: each wave owns its LDS region exclusively.
__global__ __launch_bounds__(256, 2) void vq_main(
    const float* __restrict__ z, const float* __restrict__ emb,
    const unsigned short* __restrict__ ephi, const unsigned short* __restrict__ eplo,
    const float* __restrict__ lsp,
    float* __restrict__ zq, float* __restrict__ oidx, float* __restrict__ pacc_g) {
  __shared__ __align__(16) char zplds[32768];   // 4 waves x (hi 4KB + lo 4KB), swizzled
  __shared__ float nrm[4][16];
  __shared__ float pp[KC];

  const int t  = threadIdx.x;
  const int w  = t >> 6;       // wave in block
  const int l  = t & 63;       // lane
  const int lg = l >> 4;       // 16-lane group 0..3
  const int lx = l & 15;

  const float lscale = lsp[0];
  char* const zpw_hi = zplds + w * 8192;
  char* const zpw_lo = zpw_hi + 4096;
  const bf16x8* const ebhi = (const bf16x8*)ephi;
  const bf16x8* const eblo = (const bf16x8*)eplo;

  float pacc[16];
#pragma unroll
  for (int n = 0; n < 16; ++n) pacc[n] = 0.0f;

  for (int tile = blockIdx.x * 4 + w; tile < (NTOT / 16); tile += gridDim.x * 4) {
    const int r0 = tile * 16;

    // ---- stage A: 16 rows x 128 d -> bf16 hi/lo, packed [dgrp][row][8], XOR-swizzled ----
#pragma unroll
    for (int i = 0; i < 4; ++i) {
      const int row = i * 4 + lg;
      const int dg  = lx;
      const float4* zp4 = (const float4*)(z + (size_t)(r0 + row) * DD + dg * 8);
      const float4 va = zp4[0];
      const float4 vb = zp4[1];
      float s = va.x * va.x + va.y * va.y + va.z * va.z + va.w * va.w
              + vb.x * vb.x + vb.y * vb.y + vb.z * vb.z + vb.w * vb.w;
#pragma unroll
      for (int m = 8; m >= 1; m >>= 1) s += __shfl_xor(s, m, 64);  // sum over 16 dgrp lanes
      if (lx == 0) nrm[w][row] = s;
      const float vv[8] = {va.x, va.y, va.z, va.w, vb.x, vb.y, vb.z, vb.w};
      bf16x8 hv, lv;
#pragma unroll
      for (int j = 0; j < 8; ++j) {
        const unsigned short h = f2bf(vv[j]);
        hv[j] = (short)h;
        lv[j] = (short)f2bf(vv[j] - bf2f(h));
      }
      const int boff = (((dg << 8) + (row << 4))) ^ ((dg & 7) << 4);
      *(bf16x8*)(zpw_hi + boff) = hv;
      *(bf16x8*)(zpw_lo + boff) = lv;
    }

    // ---- MFMA: acc[n] = Z_tile . E^T over 4 k-chunks; hi*hi + lo*hi + hi*lo ----
    f32x4 acc[16];
#pragma unroll
    for (int n = 0; n < 16; ++n) acc[n] = (f32x4){0.f, 0.f, 0.f, 0.f};

#pragma unroll
    for (int kc = 0; kc < 4; ++kc) {
      const int dg = kc * 4 + lg;
      const int aoff = (((dg << 8) + (lx << 4))) ^ ((dg & 7) << 4);
      const bf16x8 ahi = *(const bf16x8*)(zpw_hi + aoff);
      const bf16x8 alo = *(const bf16x8*)(zpw_lo + aoff);
      const int bbase = dg * 256 + lx;   // 16B-frag index into [16][256]
#pragma unroll
      for (int n = 0; n < 16; ++n) {
        const bf16x8 bhi = ebhi[bbase + n * 16];
        const bf16x8 blo = eblo[bbase + n * 16];
        acc[n] = __builtin_amdgcn_mfma_f32_16x16x32_bf16(ahi, bhi, acc[n], 0, 0, 0);
        acc[n] = __builtin_amdgcn_mfma_f32_16x16x32_bf16(alo, bhi, acc[n], 0, 0, 0);
        acc[n] = __builtin_amdgcn_mfma_f32_16x16x32_bf16(ahi, blo, acc[n], 0, 0, 0);
      }
    }

    // ---- epilogue: 4 reg-phases, each 16-lane group owns one row ----
#pragma unroll
    for (int r = 0; r < 4; ++r) {
      const int rowi = lg * 4 + r;
      const int R = r0 + rowi;
      const float inv = lscale / fmaxf(sqrtf(nrm[w][rowi]), 1e-12f);
      float l16[16];
#pragma unroll
      for (int n = 0; n < 16; ++n) l16[n] = acc[n][r] * inv;

      // top-1 (first-occurrence: smaller index wins on equality)
      float m1 = l16[0]; int i1 = lx;
#pragma unroll
      for (int n = 1; n < 16; ++n) {
        const int c = n * 16 + lx;
        if (l16[n] > m1) { m1 = l16[n]; i1 = c; }
      }
#pragma unroll
      for (int s = 8; s >= 1; s >>= 1) {
        const float om = __shfl_xor(m1, s, 64);
        const int   oi = __shfl_xor(i1, s, 64);
        if (om > m1 || (om == m1 && oi < i1)) { m1 = om; i1 = oi; }
      }
      // top-2
      float m2 = -3.0e38f; int i2 = 0;
#pragma unroll
      for (int n = 0; n < 16; ++n) {
        const int c = n * 16 + lx;
        if (c != i1 && l16[n] > m2) { m2 = l16[n]; i2 = c; }
      }
#pragma unroll
      for (int s = 8; s >= 1; s >>= 1) {
        const float om = __shfl_xor(m2, s, 64);
        const int   oi = __shfl_xor(i2, s, 64);
        if (om > m2 || (om == m2 && oi < i2)) { m2 = om; i2 = oi; }
      }
      // fp64 refinement for near-ties (bf16-split err ~1e-4 worst; include top-3
      // so a triple near-tie cannot hide the true argmax outside the candidate set)
      if (m1 - m2 < 1.0e-3f) {
        float m3 = -3.0e38f; int i3 = 0;
#pragma unroll
        for (int n = 0; n < 16; ++n) {
          const int c = n * 16 + lx;
          if (c != i1 && c != i2 && l16[n] > m3) { m3 = l16[n]; i3 = c; }
        }
#pragma unroll
        for (int s = 8; s >= 1; s >>= 1) {
          const float om = __shfl_xor(m3, s, 64);
          const int   oi = __shfl_xor(i3, s, 64);
          if (om > m3 || (om == m3 && oi < i3)) { m3 = om; i3 = oi; }
        }
        if (lx == 0) {
          const float* zp = z + (size_t)R * DD;
          const float* e1 = emb + (size_t)i1 * DD;
          const float* e2 = emb + (size_t)i2 * DD;
          const float* e3 = emb + (size_t)i3 * DD;
          double s1 = 0.0, s2 = 0.0, s3 = 0.0, q1 = 0.0, q2 = 0.0, q3 = 0.0;
#pragma unroll 1
          for (int d = 0; d < DD; ++d) {
            const double zd = zp[d];
            const double a1 = e1[d], a2 = e2[d], a3 = e3[d];
            s1 += zd * a1; q1 += a1 * a1;
            s2 += zd * a2; q2 += a2 * a2;
            s3 += zd * a3; q3 += a3 * a3;
          }
          const double v1 = s1 / sqrt(q1);
          const double v2 = s2 / sqrt(q2);
          const double v3 = s3 / sqrt(q3);
          double vb = v1; int ib = i1;
          if (v2 > vb || (v2 == vb && i2 < ib)) { vb = v2; ib = i2; }
          if (v3 > vb || (v3 == vb && i3 < ib)) { vb = v3; ib = i3; }
          i1 = ib;
        }
        i1 = __shfl(i1, (l & 48), 64);   // broadcast from group base lane
      }
      // softmax partial sums for avg_probs
      float se = 0.0f, pr[16];
#pragma unroll
      for (int n = 0; n < 16; ++n) { pr[n] = expf(l16[n] - m1); se += pr[n]; }
#pragma unroll
      for (int s = 8; s >= 1; s >>= 1) se += __shfl_xor(se, s, 64);
      const float rs = 1.0f / se;
#pragma unroll
      for (int n = 0; n < 16; ++n) pacc[n] = fmaf(pr[n], rs, pacc[n]);

      // outputs: gather embeddings[i1] -> z_q row; index as float
      const float4 e0 = *(const float4*)(emb + (size_t)i1 * DD + lx * 8);
      const float4 e1v = *(const float4*)(emb + (size_t)i1 * DD + lx * 8 + 4);
      *(float4*)(zq + (size_t)R * DD + lx * 8) = e0;
      *(float4*)(zq + (size_t)R * DD + lx * 8 + 4) = e1v;
      if (lx == 0) oidx[R] = (float)i1;
    }
  }

  // block-level avg_probs reduction -> one global atomic per code
  pp[t] = 0.0f;
  __syncthreads();
#pragma unroll
  for (int n = 0; n < 16; ++n) atomicAdd(&pp[n * 16 + lx], pacc[n]);
  __syncthreads();
  atomicAdd(&pacc_g[t], pp[t]);
}

// ---------------- perplexity ----------------
__global__ __launch_bounds__(256) void vq_perp(const float* __restrict__ pacc_g,
                                               float* __restrict__ outp) {
  __shared__ double red[256];
  const int t = threadIdx.x;
  const double p = (double)pacc_g[t] * (1.0 / (double)NTOT);
  red[t] = p * log(p + 1e-10);
  __syncthreads();
  for (int s = 128; s > 0; s >>= 1) {
    if (t < s) red[t] += red[t + s];
    __syncthreads();
  }
  if (t == 0) outp[0] = (float)exp(-red[0]);
}

extern "C" void kernel_launch(void* const* d_in, const int* in_sizes, int n_in,
                              void* d_out, int out_size, void* d_ws, size_t ws_size,
                              hipStream_t stream) {
  const float* z   = (const float*)d_in[0];
  const float* emb = (const float*)d_in[1];
  const float* lsp = (const float*)d_in[2];

  float* ws_probs = (float*)d_ws;                               // [256] prob accumulator
  unsigned short* ws_ephi = (unsigned short*)(ws_probs + KC);   // [16][256][8] bf16 hi
  unsigned short* ws_eplo = ws_ephi + 16 * KC * 8;              // [16][256][8] bf16 lo

  float* zq    = (float*)d_out;              // [N,128]
  float* oidx  = zq + (size_t)NTOT * DD;     // [N] indices as float
  float* operp = oidx + NTOT;                // [1]

  vq_prep<<<KC, 64, 0, stream>>>(emb, ws_ephi, ws_eplo, ws_probs);
  vq_main<<<2048, 256, 0, stream>>>(z, emb, ws_ephi, ws_eplo, lsp, zq, oidx, ws_probs);
  vq_perp<<<1, 256, 0, stream>>>(ws_probs, operp);
}